// Round 2
// baseline (123.209 us; speedup 1.0000x reference)
//
#include <hip/hip_runtime.h>

#define NROWS 4096
#define DDIM  256
#define MARGIN 0.1f
#define GX 32
#define GY 32
#define NBLOCKS (GX * GY)

typedef __attribute__((ext_vector_type(4)))  _Float16 half4;
typedef __attribute__((ext_vector_type(8)))  _Float16 half8;
typedef __attribute__((ext_vector_type(16))) float    floatx16;

// ---------------- Kernel A: diag + fp16 hi/lo split + zero rank ----------------
// Splits each fp32 x into hi=(f16)x, lo=(f16)(x-hi), RNE both — numerics
// identical to the previous in-kernel cvt8 path.
__global__ __launch_bounds__(256) void prep_kernel(
    const float* __restrict__ v, const float* __restrict__ t,
    float* __restrict__ diag, int* __restrict__ rank,
    _Float16* __restrict__ vhi, _Float16* __restrict__ vlo,
    _Float16* __restrict__ thi, _Float16* __restrict__ tlo) {
  const int wv   = threadIdx.x >> 6;
  const int lane = threadIdx.x & 63;
  const int row  = blockIdx.x * 4 + wv;
  const float4 a = ((const float4*)(v + (size_t)row * DDIM))[lane];
  const float4 b = ((const float4*)(t + (size_t)row * DDIM))[lane];

  half4 ah, al, bh, bl;
  ah.x = (_Float16)a.x; al.x = (_Float16)(a.x - (float)ah.x);
  ah.y = (_Float16)a.y; al.y = (_Float16)(a.y - (float)ah.y);
  ah.z = (_Float16)a.z; al.z = (_Float16)(a.z - (float)ah.z);
  ah.w = (_Float16)a.w; al.w = (_Float16)(a.w - (float)ah.w);
  bh.x = (_Float16)b.x; bl.x = (_Float16)(b.x - (float)bh.x);
  bh.y = (_Float16)b.y; bl.y = (_Float16)(b.y - (float)bh.y);
  bh.z = (_Float16)b.z; bl.z = (_Float16)(b.z - (float)bh.z);
  bh.w = (_Float16)b.w; bl.w = (_Float16)(b.w - (float)bh.w);

  const size_t o = (size_t)row * DDIM + lane * 4;
  *(half4*)(vhi + o) = ah;
  *(half4*)(vlo + o) = al;
  *(half4*)(thi + o) = bh;
  *(half4*)(tlo + o) = bl;

  float s = a.x*b.x + a.y*b.y + a.z*b.z + a.w*b.w;
  #pragma unroll
  for (int off = 32; off; off >>= 1) s += __shfl_down(s, off);
  if (lane == 0) { diag[row] = s; rank[row] = 0; }
}

// async global->LDS, 16B per lane, linear LDS dest (wave base + lane*16)
#define GLOAD16(gp, lp) \
  __builtin_amdgcn_global_load_lds( \
      (const __attribute__((address_space(1))) unsigned int*)(gp), \
      (__attribute__((address_space(3))) unsigned int*)(lp), 16, 0, 0)

// ---------------- Kernel B: fused MFMA GEMM + epilogue ----------------
// 128x128 block tile, 4 waves of 64x64, BK=32.
// LDS tile row = [hi 32 halves | lo 32 halves] = 128B; physical byte =
// logical ^ ((row&7)<<4) (T2 involution). Staging: linear LDS dest +
// per-lane pre-swizzled global source (plane select + slot from swizzle).
// Double-buffered with counted vmcnt(8) + raw s_barrier (T4): next slab's
// loads fly across the whole compute phase; never drain to 0 mid-loop.
__global__ __launch_bounds__(256, 2) void main_kernel(
    const _Float16* __restrict__ vhi, const _Float16* __restrict__ vlo,
    const _Float16* __restrict__ thi, const _Float16* __restrict__ tlo,
    const float* __restrict__ diag, float* __restrict__ pvt,
    float* __restrict__ ptv, int* __restrict__ rank) {
  __shared__ __align__(16) _Float16 Abuf[2][128 * 64];
  __shared__ __align__(16) _Float16 Bbuf[2][128 * 64];
  __shared__ float sdi[128];
  __shared__ float sdj[128];
  __shared__ float red[8];

  const int tid  = threadIdx.x;
  const int w    = tid >> 6;
  const int lane = tid & 63;
  const int i0   = blockIdx.y * 128;
  const int j0   = blockIdx.x * 128;

  if (tid < 128) sdi[tid] = diag[i0 + tid];
  else           sdj[tid - 128] = diag[j0 + tid - 128];

  // staging map: instr p covers 8 rows x 128B; lane l -> row w*32+p*8+(l>>3),
  // dest byte (l&7)*16 (linear). Source slot c = (l&7) ^ (row&7); c<4 -> hi
  // plane bytes (c&3)*16, c>=4 -> lo plane bytes (c&3)*16.
  const int prow = lane >> 3;            // == row & 7 (w*32, p*8 keep low bits)
  const int c    = (lane & 7) ^ prow;    // swizzled 16B slot
  const _Float16* aplane = (c < 4) ? vhi : vlo;
  const _Float16* bplane = (c < 4) ? thi : tlo;
  const _Float16* aSrc = aplane + (size_t)(i0 + w * 32 + prow) * DDIM + (c & 3) * 8;
  const _Float16* bSrc = bplane + (size_t)(j0 + w * 32 + prow) * DDIM + (c & 3) * 8;

  floatx16 acc[2][2];
  #pragma unroll
  for (int mt = 0; mt < 2; ++mt)
    #pragma unroll
    for (int nt = 0; nt < 2; ++nt)
      #pragma unroll
      for (int r = 0; r < 16; ++r) acc[mt][nt][r] = 0.f;

  const int mrow  = lane & 31;
  const int hsel  = lane >> 5;
  const int arow0 = (w >> 1) * 64 + mrow;
  const int brow0 = (w & 1) * 64 + mrow;
  const int asw   = (arow0 & 7) << 4;   // mt*32 doesn't change row&7
  const int bsw   = (brow0 & 7) << 4;

  // prologue: stage slab 0 into buf 0
  {
    char* aD = (char*)&Abuf[0][0] + w * 4096;
    char* bD = (char*)&Bbuf[0][0] + w * 4096;
    #pragma unroll
    for (int p = 0; p < 4; ++p) GLOAD16(aSrc + p * 2048, aD + p * 1024);
    #pragma unroll
    for (int p = 0; p < 4; ++p) GLOAD16(bSrc + p * 2048, bD + p * 1024);
  }

  for (int s = 0; s < 8; ++s) {
    const int cur = s & 1;
    if (s < 7) {   // issue next slab into the other buffer; 8 loads in flight
      char* aD = (char*)&Abuf[cur ^ 1][0] + w * 4096;
      char* bD = (char*)&Bbuf[cur ^ 1][0] + w * 4096;
      #pragma unroll
      for (int p = 0; p < 4; ++p)
        GLOAD16(aSrc + p * 2048 + (s + 1) * 32, aD + p * 1024);
      #pragma unroll
      for (int p = 0; p < 4; ++p)
        GLOAD16(bSrc + p * 2048 + (s + 1) * 32, bD + p * 1024);
      asm volatile("s_waitcnt vmcnt(8)" ::: "memory");   // cur slab landed
    } else {
      asm volatile("s_waitcnt vmcnt(0)" ::: "memory");
    }
    __builtin_amdgcn_sched_barrier(0);
    __builtin_amdgcn_s_barrier();                        // all waves' cur landed
    __builtin_amdgcn_sched_barrier(0);

    const _Float16* Ab = &Abuf[cur][0];
    const _Float16* Bb = &Bbuf[cur][0];
    #pragma unroll
    for (int ks = 0; ks < 2; ++ks) {
      const int cb = ks * 32 + hsel * 16;   // logical hi-plane byte col
      half8 bh[2], bl[2];
      #pragma unroll
      for (int nt = 0; nt < 2; ++nt) {
        const char* bq = (const char*)Bb + (brow0 + nt * 32) * 128;
        const int  pc = cb ^ bsw;
        bh[nt] = *(const half8*)(bq + pc);
        bl[nt] = *(const half8*)(bq + (pc ^ 64));
      }
      #pragma unroll
      for (int mt = 0; mt < 2; ++mt) {
        const char* aq = (const char*)Ab + (arow0 + mt * 32) * 128;
        const int  pa = cb ^ asw;
        const half8 ah = *(const half8*)(aq + pa);
        const half8 al = *(const half8*)(aq + (pa ^ 64));
        #pragma unroll
        for (int nt = 0; nt < 2; ++nt) {
          acc[mt][nt] = __builtin_amdgcn_mfma_f32_32x32x16_f16(al, bh[nt], acc[mt][nt], 0, 0, 0);
          acc[mt][nt] = __builtin_amdgcn_mfma_f32_32x32x16_f16(ah, bl[nt], acc[mt][nt], 0, 0, 0);
          acc[mt][nt] = __builtin_amdgcn_mfma_f32_32x32x16_f16(ah, bh[nt], acc[mt][nt], 0, 0, 0);
        }
      }
    }
    __builtin_amdgcn_sched_barrier(0);
    __builtin_amdgcn_s_barrier();                        // done reading buf[cur]
    __builtin_amdgcn_sched_barrier(0);
  }

  // ---- epilogue: C/D layout col=lane&31, row=(reg&3)+8*(reg>>2)+4*(lane>>5) ----
  float vt = 0.f, tv = 0.f;
  const int colL = lane & 31;
  #pragma unroll
  for (int mt = 0; mt < 2; ++mt) {
    const int rbase = (w >> 1) * 64 + mt * 32;
    #pragma unroll
    for (int reg = 0; reg < 16; ++reg) {
      const int r  = (reg & 3) + 8 * (reg >> 2) + 4 * hsel;
      const int gi = i0 + rbase + r;
      const float di = sdi[rbase + r];
      unsigned long long b0 = 0, b1 = 0;
      #pragma unroll
      for (int nt = 0; nt < 2; ++nt) {
        const int c2 = (w & 1) * 64 + nt * 32 + colL;
        const int gj = j0 + c2;
        const float sc = acc[mt][nt][reg];
        const float dj = sdj[c2];
        const bool ne = (gi != gj);
        if (ne) {
          vt += fmaxf(0.f, MARGIN - di + sc);
          tv += fmaxf(0.f, MARGIN - dj + sc);
        }
        const unsigned long long bb = __ballot(ne && (sc > di));
        if (nt == 0) b0 = bb; else b1 = bb;
      }
      if (colL == 0) {
        const int cc = hsel ? (int)(__popcll(b0 >> 32) + __popcll(b1 >> 32))
                            : (int)(__popcll(b0 & 0xFFFFFFFFull) + __popcll(b1 & 0xFFFFFFFFull));
        atomicAdd(&rank[gi], cc);
      }
    }
  }
  #pragma unroll
  for (int off = 32; off; off >>= 1) {
    vt += __shfl_down(vt, off);
    tv += __shfl_down(tv, off);
  }
  if (lane == 0) { red[w] = vt; red[4 + w] = tv; }
  __syncthreads();
  if (tid == 0) {
    const int bid = blockIdx.y * GX + blockIdx.x;
    pvt[bid] = red[0] + red[1] + red[2] + red[3];
    ptv[bid] = red[4] + red[5] + red[6] + red[7];
  }
}

// ---------------- Kernel C: final reduction -> 6 outputs ----------------
__global__ __launch_bounds__(256) void final_kernel(
    const float* __restrict__ pvt, const float* __restrict__ ptv,
    const int* __restrict__ rank, float* __restrict__ out) {
  __shared__ int s1[4], s5[4], s10[4], ssum[4];
  __shared__ float sv[4], st[4];
  const int tid = threadIdx.x;
  int c1 = 0, c5 = 0, c10 = 0, cs = 0;
  for (int i = tid; i < NROWS; i += 256) {
    const int r = rank[i];
    c1  += (r < 1);
    c5  += (r < 5);
    c10 += (r < 10);
    cs  += r;
  }
  float fv = 0.f, ft = 0.f;
  for (int i = tid; i < NBLOCKS; i += 256) { fv += pvt[i]; ft += ptv[i]; }
  #pragma unroll
  for (int off = 32; off; off >>= 1) {
    c1  += __shfl_down(c1, off);
    c5  += __shfl_down(c5, off);
    c10 += __shfl_down(c10, off);
    cs  += __shfl_down(cs, off);
    fv  += __shfl_down(fv, off);
    ft  += __shfl_down(ft, off);
  }
  const int w = tid >> 6;
  if ((tid & 63) == 0) { s1[w] = c1; s5[w] = c5; s10[w] = c10; ssum[w] = cs; sv[w] = fv; st[w] = ft; }
  __syncthreads();
  if (tid == 0) {
    int a1 = 0, a5 = 0, a10 = 0, as = 0; float av = 0.f, at = 0.f;
    for (int k = 0; k < 4; ++k) {
      a1 += s1[k]; a5 += s5[k]; a10 += s10[k]; as += ssum[k];
      av += sv[k]; at += st[k];
    }
    const float denom = 4096.0f * 4095.0f;
    out[0] = av / denom;
    out[1] = at / denom;
    out[2] = a1  / 4096.0f;
    out[3] = a5  / 4096.0f;
    out[4] = a10 / 4096.0f;
    out[5] = (float)as / 4096.0f;
  }
}

extern "C" void kernel_launch(void* const* d_in, const int* in_sizes, int n_in,
                              void* d_out, int out_size, void* d_ws, size_t ws_size,
                              hipStream_t stream) {
  const float* v = (const float*)d_in[0];
  const float* t = (const float*)d_in[1];
  float* out = (float*)d_out;

  char* ws = (char*)d_ws;
  float* diag = (float*)(ws);                       // 16 KB
  int*   rank = (int*)(ws + (16 << 10));            // 16 KB
  float* pvt  = (float*)(ws + (32 << 10));          // 4 KB
  float* ptv  = (float*)(ws + (36 << 10));          // 4 KB
  const size_t PLANE = (size_t)NROWS * DDIM * sizeof(_Float16);  // 2 MB
  _Float16* vhi = (_Float16*)(ws + (64 << 10));
  _Float16* vlo = (_Float16*)(ws + (64 << 10) + PLANE);
  _Float16* thi = (_Float16*)(ws + (64 << 10) + 2 * PLANE);
  _Float16* tlo = (_Float16*)(ws + (64 << 10) + 3 * PLANE);

  hipLaunchKernelGGL(prep_kernel, dim3(NROWS / 4), dim3(256), 0, stream,
                     v, t, diag, rank, vhi, vlo, thi, tlo);
  hipLaunchKernelGGL(main_kernel, dim3(GX, GY), dim3(256), 0, stream,
                     vhi, vlo, thi, tlo, diag, pvt, ptv, rank);
  hipLaunchKernelGGL(final_kernel, dim3(1), dim3(256), 0, stream, pvt, ptv, rank, out);
}